// Round 2
// baseline (1373.732 us; speedup 1.0000x reference)
//
#include <hip/hip_runtime.h>
#include <hip/hip_cooperative_groups.h>
#include <math.h>

namespace cg = cooperative_groups;

#define NEURONS 54
#define DT 4
#define STEPS 30
#define BATCH 16
#define HW 75
#define P 5625        // 75*75
#define PPAD 5632     // padded to multiple of 4 (16B float4 alignment)
#define PPAD4 (PPAD/4)
#define NFRAMES (BATCH*STEPS)   // 480
#define GRID 512
#define TPB 512
#define PAIRS (PPAD/2)          // 2816 pooled-pixel pairs per frame

// ===========================================================================
// ONE cooperative kernel: [repack + pool] -> grid.sync -> [FC] -> grid.sync
// -> [scan]. Eliminates 3 inter-kernel serialization points. All arithmetic
// bit-identical to the verified multi-kernel version (absmax must stay 0).
// ===========================================================================
__global__ __launch_bounds__(TPB, 4) void fused_all(
    const float* __restrict__ x, const float* __restrict__ fc_w,
    const float* __restrict__ fc_b, const float* __restrict__ l_weight,
    const float* __restrict__ h_weight, float* __restrict__ wpad,
    float* __restrict__ xp, float* __restrict__ frames,
    float* __restrict__ out)
{
    __shared__ __align__(16) float xp_s[PPAD];
    __shared__ float partial[NEURONS * 8];
    __shared__ float wls[16];
    cg::grid_group grid = cg::this_grid();
    const int tid = threadIdx.x;
    const int gid = blockIdx.x * TPB + tid;
    const int gstride = GRID * TPB;

    // ---- phase W: repack fc_w [54][5625] -> [54][5632] (16B-aligned rows)
    for (int idx = gid; idx < NEURONS * PPAD; idx += gstride) {
        int n = idx / PPAD, p = idx - n * PPAD;
        wpad[idx] = (p < P) ? fc_w[n * P + p] : 0.0f;
    }

    // ---- phase P: 8x8 avg-pool, TWO adjacent pooled pixels per thread so a
    // lane reads 64B contiguous per row (full cache line). Per-pixel add
    // order identical to the verified kernel -> bitwise-same xp.
    for (int g = gid; g < NFRAMES * PAIRS; g += gstride) {
        int bt = g / PAIRS, tt = g - bt * PAIRS;
        int p0 = tt * 2, p1 = p0 + 1;
        const float* img = x + (size_t)bt * (600 * 600);
        float v0 = 0.0f, v1 = 0.0f;
        if (p0 < P) {
            int ph = p0 / HW, pw = p0 - ph * HW;
            const float* base = img + (ph * 8) * 600 + pw * 8;
            float acc0 = 0.0f, acc1 = 0.0f;
            if (pw < HW - 1) {                       // p1 in same pooled row
                #pragma unroll
                for (int r = 0; r < 8; r++) {
                    const float4* row = (const float4*)(base + r * 600);
                    float4 a = row[0], b4 = row[1], c = row[2], d4 = row[3];
                    acc0 += (a.x + b4.x) + (a.y + b4.y) + (a.z + b4.z) + (a.w + b4.w);
                    acc1 += (c.x + d4.x) + (c.y + d4.y) + (c.z + d4.z) + (c.w + d4.w);
                }
                v0 = acc0 * (1.0f / 64.0f);
                v1 = acc1 * (1.0f / 64.0f);
            } else {                                 // row-wrap edge case
                #pragma unroll
                for (int r = 0; r < 8; r++) {
                    const float4* row = (const float4*)(base + r * 600);
                    float4 a = row[0], b4 = row[1];
                    acc0 += (a.x + b4.x) + (a.y + b4.y) + (a.z + b4.z) + (a.w + b4.w);
                }
                v0 = acc0 * (1.0f / 64.0f);
                if (p1 < P) {
                    int ph1 = p1 / HW, pw1 = p1 - ph1 * HW;
                    const float* base1 = img + (ph1 * 8) * 600 + pw1 * 8;
                    #pragma unroll
                    for (int r = 0; r < 8; r++) {
                        const float4* row = (const float4*)(base1 + r * 600);
                        float4 a = row[0], b4 = row[1];
                        acc1 += (a.x + b4.x) + (a.y + b4.y) + (a.z + b4.z) + (a.w + b4.w);
                    }
                    v1 = acc1 * (1.0f / 64.0f);
                }
            }
        }
        *(float2*)(xp + (size_t)bt * PPAD + p0) = make_float2(v0, v1);
    }

    __threadfence();
    grid.sync();

    // ---- phase F: one frame per block, EXACT arithmetic of verified fc_k
    if (blockIdx.x < NFRAMES) {
        const int bt = blockIdx.x;
        const float4* src = (const float4*)(xp + (size_t)bt * PPAD);
        float4* dst = (float4*)xp_s;
        for (int i = tid; i < PPAD4; i += TPB) dst[i] = src[i];
        __syncthreads();
        if (tid < NEURONS * 8) {
            int n = tid >> 3, c = tid & 7;
            const float4* w4 = (const float4*)(wpad + n * PPAD);
            const float4* x4 = (const float4*)xp_s;
            float acc = 0.0f;
            for (int i = c; i < PPAD4; i += 8) {
                float4 a = x4[i], w = w4[i];
                acc += a.x * w.x + a.y * w.y + a.z * w.z + a.w * w.w;
            }
            partial[tid] = acc;
        }
        __syncthreads();
        if (tid < NEURONS) {
            float s = 0.0f;
            #pragma unroll
            for (int c = 0; c < 8; c++) s += partial[tid * 8 + c];
            frames[bt * NEURONS + tid] = s + fc_b[tid];
        }
    }

    __threadfence();
    grid.sync();

    // ---- phase S: block 0 only. 8 waves x 2 batch-slots (b, b+8); butterfly
    // trees and wls[16] reduction bitwise-identical to verified scan_k.
    if (blockIdx.x != 0) return;
    const int w = tid >> 6, n = tid & 63;
    const bool active = (n < NEURONS);
    const int b0 = w, b1 = w + 8;
    float lw[DT], hw_[DT];
    #pragma unroll
    for (int d = 0; d < DT; d++) {
        lw[d]  = active ? l_weight[n * DT + d] : 0.0f;
        hw_[d] = h_weight[d];
    }
    float hist0[DT] = {0.f,0.f,0.f,0.f}, hist1[DT] = {0.f,0.f,0.f,0.f};
    float cnt0 = 0.f, cnt1 = 0.f;

    for (int t = 0; t < STEPS; t++) {
        float mh0 = 0.f, ht0 = 0.f, mh1 = 0.f, ht1 = 0.f;
        #pragma unroll
        for (int d = 0; d < DT; d++) {
            mh0 += hist0[d] * lw[d];  ht0 += hist0[d] * hw_[d];
            mh1 += hist1[d] * lw[d];  ht1 += hist1[d] * hw_[d];
        }
        float tot0 = mh0, tot1 = mh1;
        #pragma unroll
        for (int off = 32; off > 0; off >>= 1) {
            tot0 += __shfl_xor(tot0, off, 64);
            tot1 += __shfl_xor(tot1, off, 64);
        }
        float rate0 = 0.f, rate1 = 0.f;
        if (active) {
            rate0 = expf(frames[(b0 * STEPS + t) * NEURONS + n] + (tot0 - mh0) + ht0);
            rate1 = expf(frames[(b1 * STEPS + t) * NEURONS + n] + (tot1 - mh1) + ht1);
        }
        float rs0 = rate0, rs1 = rate1;
        #pragma unroll
        for (int off = 32; off > 0; off >>= 1) {
            rs0 += __shfl_xor(rs0, off, 64);
            rs1 += __shfl_xor(rs1, off, 64);
        }
        __syncthreads();
        if (n == 0) { wls[b0] = rs0; wls[b1] = rs1; }
        __syncthreads();
        float v = (n < 16) ? wls[n] : 0.f;
        #pragma unroll
        for (int off = 32; off > 0; off >>= 1) v += __shfl_xor(v, off, 64);
        float thr = v * (1.0f / (BATCH * NEURONS));

        float s0 = (active && rate0 > thr) ? 1.0f : 0.0f;
        float s1 = (active && rate1 > thr) ? 1.0f : 0.0f;
        cnt0 += s0; cnt1 += s1;
        hist0[0]=hist0[1]; hist0[1]=hist0[2]; hist0[2]=hist0[3]; hist0[3]=s0;
        hist1[0]=hist1[1]; hist1[1]=hist1[2]; hist1[2]=hist1[3]; hist1[3]=s1;
    }
    if (active) {
        out[b0 * NEURONS + n] = cnt0 + log1pf(expf(-cnt0));
        out[b1 * NEURONS + n] = cnt1 + log1pf(expf(-cnt1));
    }
}

// ===========================================================================
// Fallback path: the verified round-1 four-kernel sequence, used only if the
// cooperative launch is rejected by the runtime/capture.
// ===========================================================================
__global__ void repack_w(const float* __restrict__ fc_w, float* __restrict__ wpad) {
    int idx = blockIdx.x * blockDim.x + threadIdx.x;
    if (idx >= NEURONS * PPAD) return;
    int n = idx / PPAD, p = idx % PPAD;
    wpad[idx] = (p < P) ? fc_w[n * P + p] : 0.0f;
}

__global__ __launch_bounds__(256) void pool_k(
    const float* __restrict__ x, float* __restrict__ xp) {
    int idx = blockIdx.x * 256 + threadIdx.x;
    int bt = idx / PPAD;
    int p  = idx - bt * PPAD;
    if (p >= P) { xp[idx] = 0.0f; return; }
    int ph = p / HW, pw = p - ph * HW;
    const float* base = x + (size_t)bt * (600 * 600) + (ph * 8) * 600 + pw * 8;
    float acc = 0.0f;
    #pragma unroll
    for (int r = 0; r < 8; r++) {
        const float4* row = (const float4*)(base + r * 600);
        float4 a = row[0], b4 = row[1];
        acc += (a.x + b4.x) + (a.y + b4.y) + (a.z + b4.z) + (a.w + b4.w);
    }
    xp[idx] = acc * (1.0f / 64.0f);
}

__global__ __launch_bounds__(512) void fc_k(
    const float* __restrict__ xp, const float* __restrict__ wpad,
    const float* __restrict__ fc_b, float* __restrict__ frames) {
    __shared__ __align__(16) float xp_s[PPAD];
    __shared__ float partial[NEURONS * 8];
    const int bt = blockIdx.x;
    const int tid = threadIdx.x;
    {
        const float4* src = (const float4*)(xp + bt * PPAD);
        float4* dst = (float4*)xp_s;
        for (int i = tid; i < PPAD4; i += 512) dst[i] = src[i];
    }
    __syncthreads();
    if (tid < NEURONS * 8) {
        int n = tid >> 3, c = tid & 7;
        const float4* w4 = (const float4*)(wpad + n * PPAD);
        const float4* x4 = (const float4*)xp_s;
        float acc = 0.0f;
        for (int i = c; i < PPAD4; i += 8) {
            float4 a = x4[i], w = w4[i];
            acc += a.x * w.x + a.y * w.y + a.z * w.z + a.w * w.w;
        }
        partial[tid] = acc;
    }
    __syncthreads();
    if (tid < NEURONS) {
        float s = 0.0f;
        #pragma unroll
        for (int c = 0; c < 8; c++) s += partial[tid * 8 + c];
        frames[bt * NEURONS + tid] = s + fc_b[tid];
    }
}

__global__ __launch_bounds__(1024) void scan_k(
    const float* __restrict__ frames, const float* __restrict__ l_weight,
    const float* __restrict__ h_weight, float* __restrict__ out) {
    __shared__ float fr_s[NFRAMES * NEURONS];
    __shared__ float wls[16];
    const int tid = threadIdx.x;
    const int b = tid >> 6;
    const int n = tid & 63;
    const bool active = (n < NEURONS);
    for (int i = tid; i < NFRAMES * NEURONS; i += 1024) fr_s[i] = frames[i];
    float lw[DT], hw_[DT];
    #pragma unroll
    for (int d = 0; d < DT; d++) {
        lw[d]  = active ? l_weight[n * DT + d] : 0.0f;
        hw_[d] = h_weight[d];
    }
    float hist[DT] = {0.f, 0.f, 0.f, 0.f};
    float count = 0.f;
    __syncthreads();
    for (int t = 0; t < STEPS; t++) {
        float my_hsum = 0.f, hterm = 0.f;
        #pragma unroll
        for (int d = 0; d < DT; d++) {
            my_hsum += hist[d] * lw[d];
            hterm   += hist[d] * hw_[d];
        }
        float tot = my_hsum;
        #pragma unroll
        for (int off = 32; off > 0; off >>= 1) tot += __shfl_xor(tot, off, 64);
        float rate = 0.f;
        if (active) {
            float cur = fr_s[(b * STEPS + t) * NEURONS + n] + (tot - my_hsum) + hterm;
            rate = expf(cur);
        }
        float rsum = rate;
        #pragma unroll
        for (int off = 32; off > 0; off >>= 1) rsum += __shfl_xor(rsum, off, 64);
        __syncthreads();
        if (n == 0) wls[b] = rsum;
        __syncthreads();
        float v = (n < 16) ? wls[n] : 0.f;
        #pragma unroll
        for (int off = 32; off > 0; off >>= 1) v += __shfl_xor(v, off, 64);
        float thr = v * (1.0f / (BATCH * NEURONS));
        float s = (active && rate > thr) ? 1.0f : 0.0f;
        count += s;
        hist[0] = hist[1]; hist[1] = hist[2]; hist[2] = hist[3]; hist[3] = s;
    }
    if (active) {
        out[b * NEURONS + n] = count + log1pf(expf(-count));
    }
}

extern "C" void kernel_launch(void* const* d_in, const int* in_sizes, int n_in,
                              void* d_out, int out_size, void* d_ws, size_t ws_size,
                              hipStream_t stream) {
    const float* x        = (const float*)d_in[0];
    const float* fc_w     = (const float*)d_in[1];
    const float* fc_b     = (const float*)d_in[2];
    const float* l_weight = (const float*)d_in[3];
    const float* h_weight = (const float*)d_in[4];
    float* out = (float*)d_out;

    float* wpad   = (float*)d_ws;                 // 54*5632 floats  = 1.22 MB
    float* xp     = wpad + NEURONS * PPAD;        // 480*5632 floats = 10.8 MB
    float* frames = xp + NFRAMES * PPAD;          // 480*54 floats   = 104 KB

    void* args[] = { (void*)&x, (void*)&fc_w, (void*)&fc_b, (void*)&l_weight,
                     (void*)&h_weight, (void*)&wpad, (void*)&xp, (void*)&frames,
                     (void*)&out };
    hipError_t err = hipLaunchCooperativeKernel((const void*)fused_all,
                                                dim3(GRID), dim3(TPB),
                                                args, 0, stream);
    if (err != hipSuccess) {
        // fallback: verified 4-kernel path
        int wtotal = NEURONS * PPAD;
        repack_w<<<(wtotal + 511) / 512, 512, 0, stream>>>(fc_w, wpad);
        pool_k<<<(NFRAMES * PPAD) / 256, 256, 0, stream>>>(x, xp);
        fc_k<<<NFRAMES, 512, 0, stream>>>(xp, wpad, fc_b, frames);
        scan_k<<<1, 1024, 0, stream>>>(frames, l_weight, h_weight, out);
    }
}